// Round 10
// baseline (118.164 us; speedup 1.0000x reference)
//
#include <hip/hip_runtime.h>

#define IN_CH 256
#define OUT_CH 512
#define HW 56
#define NPIX (HW * HW)            // 3136
#define NPIX4 (NPIX / 4)          // 784
#define WROW (IN_CH * 9)          // 2304
#define NT 10
#define HB 8
#define NDOT (NT * HB)            // 80
#define SIZE_LIMIT 256
#define EPS 1e-3f

// stage1 roles: weight-sig (WOTILE=4) + query + zero-y
#define WOTILE 4
#define WBLOCKS ((OUT_CH / WOTILE) * NT)        // 1280
#define QBLOCKS IN_CH                           // 256
#define ZBLOCKS OUT_CH                          // 512
#define S1BLOCKS (WBLOCKS + QBLOCKS + ZBLOCKS)  // 2048

// conv tiling: 4 px/thread (float4), 2 out-ch, 16 in-ch per block
#define COTILE 2
#define COTILES (SIZE_LIMIT / COTILE)           // 128
#define PT4 4                                   // ceil(784/256)
#define KSPLIT 16
#define KCH (IN_CH / KSPLIT)                    // 16
#define WPB (COTILE * KCH * 9)                  // 288 floats

// ws offsets (4-byte units)
#define Q_OFF       0
#define QADDR_OFF   256
#define WADDR_OFF   288
#define SLOT_OFF    (WADDR_OFF + NT * OUT_CH)
#define NACT_OFF    (SLOT_OFF + OUT_CH)
#define COMPACT_OFF (NACT_OFF + 32)
#define PART_OFF    16384                       // 16*256*3136 f ≈ 51.4 MB

// ---- 1. fused: weight signatures + global-avg-pool query + zero y ----
__global__ __launch_bounds__(256) void k_stage1(const float* __restrict__ x,
                                                const float* __restrict__ whole_w,
                                                const float* __restrict__ rm_w,
                                                float* __restrict__ wsf,
                                                int* __restrict__ wsi,
                                                float* __restrict__ y) {
    __shared__ float4 sW4[WOTILE][WROW / 4];  // 36.9 KB
    __shared__ int bits[HB][WOTILE];
    __shared__ float red[256];
    int bid = blockIdx.x, tid = threadIdx.x;

    if (bid < WBLOCKS) {
        int ogrp = bid / NT, dg = bid - ogrp * NT;
        int o0 = ogrp * WOTILE;
        const float4* w4 = (const float4*)(whole_w + (size_t)o0 * WROW);
        for (int i = tid; i < WOTILE * (WROW / 4); i += 256)
            sW4[i / (WROW / 4)][i % (WROW / 4)] = w4[i];
        __syncthreads();
        int wid = tid >> 6, lane = tid & 63;
        int d0 = dg * HB + wid * 2;   // block covers all 8 bits of table dg
        const float4* r0 = (const float4*)(rm_w + (size_t)d0 * WROW);
        const float4* r1 = (const float4*)(rm_w + (size_t)(d0 + 1) * WROW);
        float a0[WOTILE], a1[WOTILE];
        #pragma unroll
        for (int j = 0; j < WOTILE; j++) { a0[j] = 0.f; a1[j] = 0.f; }
        for (int i = lane; i < WROW / 4; i += 64) {  // 9 iters
            float4 v0 = r0[i], v1 = r1[i];
            #pragma unroll
            for (int j = 0; j < WOTILE; j++) {
                float4 w = sW4[j][i];
                a0[j] += v0.x * w.x + v0.y * w.y + v0.z * w.z + v0.w * w.w;
                a1[j] += v1.x * w.x + v1.y * w.y + v1.z * w.z + v1.w * w.w;
            }
        }
        #pragma unroll
        for (int j = 0; j < WOTILE; j++) {
            for (int m = 32; m > 0; m >>= 1) {
                a0[j] += __shfl_xor(a0[j], m, 64);
                a1[j] += __shfl_xor(a1[j], m, 64);
            }
        }
        if (lane == 0) {
            #pragma unroll
            for (int j = 0; j < WOTILE; j++) {
                bits[wid * 2][j]     = (a0[j] > 0.f) ? 1 : 0;
                bits[wid * 2 + 1][j] = (a1[j] > 0.f) ? 1 : 0;
            }
        }
        __syncthreads();
        if (tid < WOTILE) {
            int a = 0;
            #pragma unroll
            for (int h = 0; h < HB; h++) a |= bits[h][tid] << (7 - h);
            wsi[WADDR_OFF + dg * OUT_CH + o0 + tid] = a;
        }
    } else if (bid < WBLOCKS + QBLOCKS) {
        int c = bid - WBLOCKS;
        const float* xc = x + (size_t)c * NPIX;
        float s = 0.f;
        for (int p = tid; p < NPIX; p += 256) s += xc[p];
        red[tid] = s;
        __syncthreads();
        for (int off = 128; off > 0; off >>= 1) {
            if (tid < off) red[tid] += red[tid + off];
            __syncthreads();
        }
        if (tid == 0) wsf[Q_OFF + c] = red[0] / (float)NPIX;
    } else {
        int o = bid - WBLOCKS - QBLOCKS;
        float4* y4 = (float4*)(y + (size_t)o * NPIX);
        float4 z4 = make_float4(0.f, 0.f, 0.f, 0.f);
        for (int i = tid; i < NPIX4; i += 256) y4[i] = z4;
    }
}

// ---- 2. fused: query signatures + histogram + top-k + compaction (512 thr) ----
__global__ void k_select(const float* __restrict__ rm_q, const float* __restrict__ wsf,
                         int* __restrict__ wsi) {
    int tid = threadIdx.x; // 512
    __shared__ float qs[IN_CH];
    __shared__ int qbits[NDOT];
    __shared__ int qsig[NT];
    __shared__ int hist[OUT_CH];
    __shared__ int sel[OUT_CH];
    if (tid < IN_CH) qs[tid] = wsf[Q_OFF + tid];
    __syncthreads();
    if (tid < NDOT * 4) {
        int d = tid >> 2, part = tid & 3;
        const float* r = rm_q + d * IN_CH + part * 64;
        const float* qq = qs + part * 64;
        float acc = 0.f;
        for (int k = 0; k < 64; k++) acc = fmaf(r[k], qq[k], acc);
        acc += __shfl_xor(acc, 1, 64);
        acc += __shfl_xor(acc, 2, 64);
        if (part == 0) qbits[d] = (acc > 0.f) ? 1 : 0;
    }
    __syncthreads();
    if (tid < NT) {
        int a = 0;
        #pragma unroll
        for (int h = 0; h < HB; h++) a |= qbits[tid * HB + h] << (7 - h);
        qsig[tid] = a;
        wsi[QADDR_OFF + tid] = a;
    }
    __syncthreads();
    int h = 0;
    for (int t = 0; t < NT; t++) h += (wsi[WADDR_OFF + t * OUT_CH + tid] == qsig[t]) ? 1 : 0;
    hist[tid] = h;
    __syncthreads();
    int rank = 0;
    for (int j = 0; j < OUT_CH; j++) {
        int hj = hist[j];
        rank += (hj > h || (hj == h && j < tid)) ? 1 : 0;
    }
    int s = (h > 0 && rank < SIZE_LIMIT) ? 1 : 0;
    sel[tid] = s;
    wsi[SLOT_OFF + tid] = 0;
    __syncthreads();
    if (s) {
        int pos = 0;
        for (int j = 0; j < tid; j++) pos += sel[j];
        wsi[COMPACT_OFF + pos] = tid;
        wsi[SLOT_OFF + tid] = pos + 1;
    }
    if (tid == 0) {
        int c = 0;
        for (int j = 0; j < OUT_CH; j++) c += sel[j];
        wsi[NACT_OFF] = c;
    }
}

// ---- 3. sparse conv: 4 px/thread float4, 2 out-ch, 16 in-ch -> partial slabs ----
__global__ __launch_bounds__(256) void k_conv(const float* __restrict__ x,
                                              const float* __restrict__ whole_w,
                                              const int* __restrict__ wsi,
                                              float* __restrict__ wsf) {
    int nact = wsi[NACT_OFF];
    int slot0 = blockIdx.y * COTILE;
    if (slot0 >= nact) return;
    int tid = threadIdx.x;
    int z = blockIdx.z;

    __shared__ float wl[COTILE][KCH * 9];   // 1.15 KB
    __shared__ int och[COTILE];
    if (tid < COTILE)
        och[tid] = (slot0 + tid < nact) ? wsi[COMPACT_OFF + slot0 + tid] : -1;
    __syncthreads();
    for (int i = tid; i < WPB; i += 256) {
        int j = i / (KCH * 9), wi = i - j * (KCH * 9);
        int o = (och[j] >= 0) ? och[j] : och[0];
        wl[j][wi] = whole_w[(size_t)o * WROW + z * (KCH * 9) + wi];
    }
    __syncthreads();

    int i4 = blockIdx.x * 256 + tid;       // float4-pixel index
    bool pv = i4 < NPIX4;
    int i4c = pv ? i4 : 0;
    int r = i4c / 14, g4 = i4c - r * 14;   // row, float4-group (56 = 4*14)
    const float* xb = x + (size_t)z * KCH * NPIX;

    float acc[COTILE][4];
    #pragma unroll
    for (int jj = 0; jj < COTILE; jj++)
        #pragma unroll
        for (int jp = 0; jp < 4; jp++) acc[jj][jp] = 0.f;

    for (int c = 0; c < KCH; c++) {
        const float* xc = xb + (size_t)c * NPIX;
        float v[3][6];   // rows r-1..r+1, cols 4g4-1 .. 4g4+4
        #pragma unroll
        for (int kh = 0; kh < 3; kh++) {
            int rr = r + kh - 1;
            bool rv = (rr >= 0) && (rr < HW);
            const float* xr = xc + (size_t)(rv ? rr : r) * HW + 4 * g4;
            float4 m = rv ? *(const float4*)xr : make_float4(0.f, 0.f, 0.f, 0.f);
            v[kh][1] = m.x; v[kh][2] = m.y; v[kh][3] = m.z; v[kh][4] = m.w;
            v[kh][0] = (rv && g4 > 0) ? xr[-1] : 0.f;
            v[kh][5] = (rv && g4 < 13) ? xr[4] : 0.f;
        }
        #pragma unroll
        for (int kh = 0; kh < 3; kh++)
            #pragma unroll
            for (int kw = 0; kw < 3; kw++) {
                int wi = c * 9 + kh * 3 + kw;
                #pragma unroll
                for (int jj = 0; jj < COTILE; jj++) {
                    float wv = wl[jj][wi];
                    #pragma unroll
                    for (int jp = 0; jp < 4; jp++)
                        acc[jj][jp] = fmaf(v[kh][jp + kw], wv, acc[jj][jp]);
                }
            }
    }
    if (pv) {
        #pragma unroll
        for (int jj = 0; jj < COTILE; jj++) {
            if (och[jj] >= 0) {
                float4 o4 = make_float4(acc[jj][0], acc[jj][1], acc[jj][2], acc[jj][3]);
                *(float4*)(wsf + PART_OFF +
                           ((size_t)z * SIZE_LIMIT + slot0 + jj) * NPIX + 4 * (size_t)i4) = o4;
            }
        }
    }
}

// ---- 4. combine 16 slabs + BN (batch stats) + ReLU, register-resident ----
__global__ __launch_bounds__(256) void k_fin(const int* __restrict__ wsi,
                                             const float* __restrict__ wsf,
                                             const float* __restrict__ gamma,
                                             const float* __restrict__ beta,
                                             float* __restrict__ y) {
    int s = blockIdx.x, tid = threadIdx.x;
    if (s >= wsi[NACT_OFF]) return;
    int o = wsi[COMPACT_OFF + s];
    float4 vv[4];
    float sum = 0.f, sq = 0.f;
    #pragma unroll
    for (int k = 0; k < 4; k++) {
        int i4 = tid + k * 256;
        float4 a = make_float4(0.f, 0.f, 0.f, 0.f);
        if (i4 < NPIX4) {
            const float* base = wsf + PART_OFF + (size_t)s * NPIX + 4 * (size_t)i4;
            #pragma unroll
            for (int z = 0; z < KSPLIT; z++) {
                float4 t = *(const float4*)(base + (size_t)z * SIZE_LIMIT * NPIX);
                a.x += t.x; a.y += t.y; a.z += t.z; a.w += t.w;
            }
        }
        vv[k] = a;
        sum += a.x + a.y + a.z + a.w;
        sq  += a.x * a.x + a.y * a.y + a.z * a.z + a.w * a.w;
    }
    __shared__ float rs[256], rq[256];
    __shared__ float mv[2];
    rs[tid] = sum; rq[tid] = sq;
    __syncthreads();
    for (int off = 128; off > 0; off >>= 1) {
        if (tid < off) { rs[tid] += rs[tid + off]; rq[tid] += rq[tid + off]; }
        __syncthreads();
    }
    if (tid == 0) {
        float mean = rs[0] / (float)NPIX;
        float var = rq[0] / (float)NPIX - mean * mean;
        float inv = 1.0f / sqrtf(var + EPS);
        float scale = inv * gamma[o];
        mv[0] = scale;
        mv[1] = beta[o] - mean * scale;
    }
    __syncthreads();
    float scale = mv[0], shift = mv[1];
    float4* y4 = (float4*)(y + (size_t)o * NPIX);
    #pragma unroll
    for (int k = 0; k < 4; k++) {
        int i4 = tid + k * 256;
        if (i4 < NPIX4) {
            float4 a = vv[k];
            a.x = fmaf(a.x, scale, shift); a.x = (a.x > 0.f) ? a.x : 0.f;
            a.y = fmaf(a.y, scale, shift); a.y = (a.y > 0.f) ? a.y : 0.f;
            a.z = fmaf(a.z, scale, shift); a.z = (a.z > 0.f) ? a.z : 0.f;
            a.w = fmaf(a.w, scale, shift); a.w = (a.w > 0.f) ? a.w : 0.f;
            y4[i4] = a;
        }
    }
}

extern "C" void kernel_launch(void* const* d_in, const int* in_sizes, int n_in,
                              void* d_out, int out_size, void* d_ws, size_t ws_size,
                              hipStream_t stream) {
    const float* x       = (const float*)d_in[0];
    const float* whole_w = (const float*)d_in[1];
    const float* rm_w    = (const float*)d_in[2];
    const float* rm_q    = (const float*)d_in[3];
    const float* gamma   = (const float*)d_in[4];
    const float* beta    = (const float*)d_in[5];
    float* out = (float*)d_out;
    float* wsf = (float*)d_ws;
    int*   wsi = (int*)d_ws;

    k_stage1<<<S1BLOCKS, 256, 0, stream>>>(x, whole_w, rm_w, wsf, wsi, out);
    k_select<<<1, OUT_CH, 0, stream>>>(rm_q, wsf, wsi);
    k_conv<<<dim3(PT4, COTILES, KSPLIT), 256, 0, stream>>>(x, whole_w, wsi, wsf);
    k_fin<<<SIZE_LIMIT, 256, 0, stream>>>(wsi, wsf, gamma, beta, out);
}

// Round 11
// 70.824 us; speedup vs baseline: 1.6684x; 1.6684x over previous
//
#include <hip/hip_runtime.h>

#define IN_CH 256
#define OUT_CH 512
#define HW 56
#define NPIX (HW * HW)            // 3136
#define NPIX4 (NPIX / 4)          // 784
#define WROW (IN_CH * 9)          // 2304
#define NT 10
#define HB 8
#define NDOT (NT * HB)            // 80
#define SIZE_LIMIT 256
#define EPS 1e-3f

// stage1 roles: weight-sig (WOTILE=4) + query + zero-y + pad-x
#define WOTILE 4
#define WBLOCKS ((OUT_CH / WOTILE) * NT)        // 1280
#define QBLOCKS IN_CH                           // 256
#define ZBLOCKS OUT_CH                          // 512
#define PBLOCKS IN_CH                           // 256
#define S1BLOCKS (WBLOCKS + QBLOCKS + ZBLOCKS + PBLOCKS)  // 2304

// conv tiling: 4 px/thread (float4), 2 out-ch, 16 in-ch, slot-pair loop
#define COTILE 2
#define SPGRID 16                               // grid.y; loop covers nact<=256
#define PT4 4                                   // ceil(784/256)
#define KSPLIT 16
#define KCH (IN_CH / KSPLIT)                    // 16

// padded x: [58 rows][64 cols] per channel; source (r,c) at (r+1,c+1)
#define XPW 64
#define XPSZ (58 * XPW)                         // 3712 floats

// ws offsets (4-byte units)
#define Q_OFF       0
#define QADDR_OFF   256
#define WADDR_OFF   288
#define SLOT_OFF    (WADDR_OFF + NT * OUT_CH)
#define NACT_OFF    (SLOT_OFF + OUT_CH)
#define COMPACT_OFF (NACT_OFF + 32)
#define PART_OFF    16384                       // 16*256*3136 f ≈ 51.4 MB
#define XPAD_OFF    (PART_OFF + KSPLIT * SIZE_LIMIT * NPIX)  // + 3.8 MB

// 12 FMAs for one (row, out-ch) group. A = padded cols [4g4..4g4+3],
// B = [4g4+4..4g4+7]; output px jp uses padded cols jp..jp+2.
#define ROWFMA(ax, ay, az, aw, A, B, k0, k1, k2)                 \
    ax = fmaf(A.x, k0, fmaf(A.y, k1, fmaf(A.z, k2, ax)));        \
    ay = fmaf(A.y, k0, fmaf(A.z, k1, fmaf(A.w, k2, ay)));        \
    az = fmaf(A.z, k0, fmaf(A.w, k1, fmaf(B.x, k2, az)));        \
    aw = fmaf(A.w, k0, fmaf(B.x, k1, fmaf(B.y, k2, aw)));

// ---- 1. fused: weight signatures + query avg-pool + zero y + pad x ----
__global__ __launch_bounds__(256) void k_stage1(const float* __restrict__ x,
                                                const float* __restrict__ whole_w,
                                                const float* __restrict__ rm_w,
                                                float* __restrict__ wsf,
                                                int* __restrict__ wsi,
                                                float* __restrict__ y) {
    __shared__ float4 sW4[WOTILE][WROW / 4];  // 36.9 KB
    __shared__ int bits[HB][WOTILE];
    __shared__ float red[256];
    int bid = blockIdx.x, tid = threadIdx.x;

    if (bid < WBLOCKS) {
        int ogrp = bid / NT, dg = bid - ogrp * NT;
        int o0 = ogrp * WOTILE;
        const float4* w4 = (const float4*)(whole_w + (size_t)o0 * WROW);
        for (int i = tid; i < WOTILE * (WROW / 4); i += 256)
            sW4[i / (WROW / 4)][i % (WROW / 4)] = w4[i];
        __syncthreads();
        int wid = tid >> 6, lane = tid & 63;
        int d0 = dg * HB + wid * 2;   // block covers all 8 bits of table dg
        const float4* r0 = (const float4*)(rm_w + (size_t)d0 * WROW);
        const float4* r1 = (const float4*)(rm_w + (size_t)(d0 + 1) * WROW);
        float a00 = 0.f, a01 = 0.f, a02 = 0.f, a03 = 0.f;
        float a10 = 0.f, a11 = 0.f, a12 = 0.f, a13 = 0.f;
        for (int i = lane; i < WROW / 4; i += 64) {  // 9 iters
            float4 v0 = r0[i], v1 = r1[i];
            float4 w0 = sW4[0][i], w1 = sW4[1][i], w2 = sW4[2][i], w3 = sW4[3][i];
            a00 += v0.x * w0.x + v0.y * w0.y + v0.z * w0.z + v0.w * w0.w;
            a01 += v0.x * w1.x + v0.y * w1.y + v0.z * w1.z + v0.w * w1.w;
            a02 += v0.x * w2.x + v0.y * w2.y + v0.z * w2.z + v0.w * w2.w;
            a03 += v0.x * w3.x + v0.y * w3.y + v0.z * w3.z + v0.w * w3.w;
            a10 += v1.x * w0.x + v1.y * w0.y + v1.z * w0.z + v1.w * w0.w;
            a11 += v1.x * w1.x + v1.y * w1.y + v1.z * w1.z + v1.w * w1.w;
            a12 += v1.x * w2.x + v1.y * w2.y + v1.z * w2.z + v1.w * w2.w;
            a13 += v1.x * w3.x + v1.y * w3.y + v1.z * w3.z + v1.w * w3.w;
        }
        for (int m = 32; m > 0; m >>= 1) {
            a00 += __shfl_xor(a00, m, 64); a01 += __shfl_xor(a01, m, 64);
            a02 += __shfl_xor(a02, m, 64); a03 += __shfl_xor(a03, m, 64);
            a10 += __shfl_xor(a10, m, 64); a11 += __shfl_xor(a11, m, 64);
            a12 += __shfl_xor(a12, m, 64); a13 += __shfl_xor(a13, m, 64);
        }
        if (lane == 0) {
            bits[wid * 2][0] = (a00 > 0.f) ? 1 : 0;
            bits[wid * 2][1] = (a01 > 0.f) ? 1 : 0;
            bits[wid * 2][2] = (a02 > 0.f) ? 1 : 0;
            bits[wid * 2][3] = (a03 > 0.f) ? 1 : 0;
            bits[wid * 2 + 1][0] = (a10 > 0.f) ? 1 : 0;
            bits[wid * 2 + 1][1] = (a11 > 0.f) ? 1 : 0;
            bits[wid * 2 + 1][2] = (a12 > 0.f) ? 1 : 0;
            bits[wid * 2 + 1][3] = (a13 > 0.f) ? 1 : 0;
        }
        __syncthreads();
        if (tid < WOTILE) {
            int a = 0;
            #pragma unroll
            for (int h = 0; h < HB; h++) a |= bits[h][tid] << (7 - h);
            wsi[WADDR_OFF + dg * OUT_CH + o0 + tid] = a;
        }
    } else if (bid < WBLOCKS + QBLOCKS) {
        int c = bid - WBLOCKS;
        const float* xc = x + (size_t)c * NPIX;
        float s = 0.f;
        for (int p = tid; p < NPIX; p += 256) s += xc[p];
        red[tid] = s;
        __syncthreads();
        for (int off = 128; off > 0; off >>= 1) {
            if (tid < off) red[tid] += red[tid + off];
            __syncthreads();
        }
        if (tid == 0) wsf[Q_OFF + c] = red[0] / (float)NPIX;
    } else if (bid < WBLOCKS + QBLOCKS + ZBLOCKS) {
        int o = bid - WBLOCKS - QBLOCKS;
        float4* y4 = (float4*)(y + (size_t)o * NPIX);
        float4 z4 = make_float4(0.f, 0.f, 0.f, 0.f);
        for (int i = tid; i < NPIX4; i += 256) y4[i] = z4;
    } else {
        // pad role: channel c -> [58][64] zero-padded tile
        int c = bid - WBLOCKS - QBLOCKS - ZBLOCKS;
        const float* xc = x + (size_t)c * NPIX;
        float* xp = wsf + XPAD_OFF + (size_t)c * XPSZ;
        for (int i = tid; i < XPSZ; i += 256) {
            int rr = i >> 6, cc = i & 63;
            int sr = rr - 1, sc = cc - 1;
            float v = (sr >= 0 && sr < HW && sc >= 0 && sc < HW) ? xc[sr * HW + sc] : 0.f;
            xp[i] = v;
        }
    }
}

// ---- 2. fused: query signatures + histogram + top-k + compaction (512 thr) ----
__global__ void k_select(const float* __restrict__ rm_q, const float* __restrict__ wsf,
                         int* __restrict__ wsi) {
    int tid = threadIdx.x; // 512
    __shared__ float qs[IN_CH];
    __shared__ int qbits[NDOT];
    __shared__ int qsig[NT];
    __shared__ int hist[OUT_CH];
    __shared__ int sel[OUT_CH];
    if (tid < IN_CH) qs[tid] = wsf[Q_OFF + tid];
    __syncthreads();
    if (tid < NDOT * 4) {
        int d = tid >> 2, part = tid & 3;
        const float* r = rm_q + d * IN_CH + part * 64;
        const float* qq = qs + part * 64;
        float acc = 0.f;
        for (int k = 0; k < 64; k++) acc = fmaf(r[k], qq[k], acc);
        acc += __shfl_xor(acc, 1, 64);
        acc += __shfl_xor(acc, 2, 64);
        if (part == 0) qbits[d] = (acc > 0.f) ? 1 : 0;
    }
    __syncthreads();
    if (tid < NT) {
        int a = 0;
        #pragma unroll
        for (int h = 0; h < HB; h++) a |= qbits[tid * HB + h] << (7 - h);
        qsig[tid] = a;
        wsi[QADDR_OFF + tid] = a;
    }
    __syncthreads();
    int h = 0;
    for (int t = 0; t < NT; t++) h += (wsi[WADDR_OFF + t * OUT_CH + tid] == qsig[t]) ? 1 : 0;
    hist[tid] = h;
    __syncthreads();
    int rank = 0;
    for (int j = 0; j < OUT_CH; j++) {
        int hj = hist[j];
        rank += (hj > h || (hj == h && j < tid)) ? 1 : 0;
    }
    int s = (h > 0 && rank < SIZE_LIMIT) ? 1 : 0;
    sel[tid] = s;
    wsi[SLOT_OFF + tid] = 0;
    __syncthreads();
    if (s) {
        int pos = 0;
        for (int j = 0; j < tid; j++) pos += sel[j];
        wsi[COMPACT_OFF + pos] = tid;
        wsi[SLOT_OFF + tid] = pos + 1;
    }
    if (tid == 0) {
        int c = 0;
        for (int j = 0; j < OUT_CH; j++) c += sel[j];
        wsi[NACT_OFF] = c;
    }
}

// ---- 3. sparse conv on padded x: named scalars only, no masks, no arrays ----
__global__ __launch_bounds__(256) void k_conv(const float* __restrict__ whole_w,
                                              const int* __restrict__ wsi,
                                              float* __restrict__ wsf) {
    int nact = wsi[NACT_OFF];
    int tid = threadIdx.x;
    int z = blockIdx.z;
    int i4 = blockIdx.x * 256 + tid;
    bool pv = i4 < NPIX4;
    int i4c = pv ? i4 : 0;
    int r = i4c / 14, g4 = i4c - r * 14;   // output row, float4-group (56 = 4*14)
    // padded rows r, r+1, r+2 = source rows r-1, r, r+1; cols 4g4.. = source 4g4-1..
    const float* xpb = wsf + XPAD_OFF + (size_t)z * KCH * XPSZ + r * XPW + 4 * g4;

    for (int sp = blockIdx.y; sp * COTILE < nact; sp += SPGRID) {
        int slot0 = sp * COTILE;
        bool s1v = (slot0 + 1) < nact;
        int o0 = wsi[COMPACT_OFF + slot0];
        int o1 = s1v ? wsi[COMPACT_OFF + slot0 + 1] : o0;
        int ou0 = __builtin_amdgcn_readfirstlane(o0);
        int ou1 = __builtin_amdgcn_readfirstlane(o1);
        const float* wp0 = whole_w + (size_t)ou0 * WROW + z * (KCH * 9);
        const float* wp1 = whole_w + (size_t)ou1 * WROW + z * (KCH * 9);

        float a0x = 0.f, a0y = 0.f, a0z = 0.f, a0w = 0.f;
        float a1x = 0.f, a1y = 0.f, a1z = 0.f, a1w = 0.f;
        for (int c = 0; c < KCH; ++c) {
            const float* xc = xpb + (size_t)c * XPSZ;
            float4 t0a = *(const float4*)(xc);
            float4 t0b = *(const float4*)(xc + 4);
            float4 t1a = *(const float4*)(xc + XPW);
            float4 t1b = *(const float4*)(xc + XPW + 4);
            float4 t2a = *(const float4*)(xc + 2 * XPW);
            float4 t2b = *(const float4*)(xc + 2 * XPW + 4);
            const float* w0 = wp0 + c * 9;
            const float* w1 = wp1 + c * 9;
            ROWFMA(a0x, a0y, a0z, a0w, t0a, t0b, w0[0], w0[1], w0[2])
            ROWFMA(a0x, a0y, a0z, a0w, t1a, t1b, w0[3], w0[4], w0[5])
            ROWFMA(a0x, a0y, a0z, a0w, t2a, t2b, w0[6], w0[7], w0[8])
            ROWFMA(a1x, a1y, a1z, a1w, t0a, t0b, w1[0], w1[1], w1[2])
            ROWFMA(a1x, a1y, a1z, a1w, t1a, t1b, w1[3], w1[4], w1[5])
            ROWFMA(a1x, a1y, a1z, a1w, t2a, t2b, w1[6], w1[7], w1[8])
        }
        if (pv) {
            float* pb = wsf + PART_OFF + ((size_t)z * SIZE_LIMIT + slot0) * NPIX + 4 * (size_t)i4;
            *(float4*)pb = make_float4(a0x, a0y, a0z, a0w);
            if (s1v) *(float4*)(pb + NPIX) = make_float4(a1x, a1y, a1z, a1w);
        }
    }
}

// ---- 4. combine 16 slabs + BN (batch stats) + ReLU, named registers ----
#define SLABSUM(dst, idx4)                                                      \
    dst = make_float4(0.f, 0.f, 0.f, 0.f);                                      \
    if ((idx4) < NPIX4) {                                                       \
        const float* bp = base0 + 4 * (size_t)(idx4);                           \
        _Pragma("unroll")                                                       \
        for (int zz = 0; zz < KSPLIT; zz++) {                                   \
            float4 t = *(const float4*)(bp + (size_t)zz * SIZE_LIMIT * NPIX);   \
            dst.x += t.x; dst.y += t.y; dst.z += t.z; dst.w += t.w;             \
        }                                                                       \
    }

#define BNSTORE(src, idx4)                                                      \
    if ((idx4) < NPIX4) {                                                       \
        float4 a = src;                                                         \
        a.x = fmaf(a.x, scale, shift); a.x = (a.x > 0.f) ? a.x : 0.f;           \
        a.y = fmaf(a.y, scale, shift); a.y = (a.y > 0.f) ? a.y : 0.f;           \
        a.z = fmaf(a.z, scale, shift); a.z = (a.z > 0.f) ? a.z : 0.f;           \
        a.w = fmaf(a.w, scale, shift); a.w = (a.w > 0.f) ? a.w : 0.f;           \
        y4[idx4] = a;                                                           \
    }

__global__ __launch_bounds__(256) void k_fin(const int* __restrict__ wsi,
                                             const float* __restrict__ wsf,
                                             const float* __restrict__ gamma,
                                             const float* __restrict__ beta,
                                             float* __restrict__ y) {
    int s = blockIdx.x, tid = threadIdx.x;
    if (s >= wsi[NACT_OFF]) return;
    int o = wsi[COMPACT_OFF + s];
    const float* base0 = wsf + PART_OFF + (size_t)s * NPIX;
    float4 v0, v1, v2, v3;
    SLABSUM(v0, tid)
    SLABSUM(v1, tid + 256)
    SLABSUM(v2, tid + 512)
    SLABSUM(v3, tid + 768)
    float sum = (v0.x + v0.y + v0.z + v0.w) + (v1.x + v1.y + v1.z + v1.w) +
                (v2.x + v2.y + v2.z + v2.w) + (v3.x + v3.y + v3.z + v3.w);
    float sq = (v0.x * v0.x + v0.y * v0.y + v0.z * v0.z + v0.w * v0.w) +
               (v1.x * v1.x + v1.y * v1.y + v1.z * v1.z + v1.w * v1.w) +
               (v2.x * v2.x + v2.y * v2.y + v2.z * v2.z + v2.w * v2.w) +
               (v3.x * v3.x + v3.y * v3.y + v3.z * v3.z + v3.w * v3.w);
    __shared__ float rs[256], rq[256];
    __shared__ float mv[2];
    rs[tid] = sum; rq[tid] = sq;
    __syncthreads();
    for (int off = 128; off > 0; off >>= 1) {
        if (tid < off) { rs[tid] += rs[tid + off]; rq[tid] += rq[tid + off]; }
        __syncthreads();
    }
    if (tid == 0) {
        float mean = rs[0] / (float)NPIX;
        float var = rq[0] / (float)NPIX - mean * mean;
        float inv = 1.0f / sqrtf(var + EPS);
        float sc = inv * gamma[o];
        mv[0] = sc;
        mv[1] = beta[o] - mean * sc;
    }
    __syncthreads();
    float scale = mv[0], shift = mv[1];
    float4* y4 = (float4*)(y + (size_t)o * NPIX);
    BNSTORE(v0, tid)
    BNSTORE(v1, tid + 256)
    BNSTORE(v2, tid + 512)
    BNSTORE(v3, tid + 768)
}

extern "C" void kernel_launch(void* const* d_in, const int* in_sizes, int n_in,
                              void* d_out, int out_size, void* d_ws, size_t ws_size,
                              hipStream_t stream) {
    const float* x       = (const float*)d_in[0];
    const float* whole_w = (const float*)d_in[1];
    const float* rm_w    = (const float*)d_in[2];
    const float* rm_q    = (const float*)d_in[3];
    const float* gamma   = (const float*)d_in[4];
    const float* beta    = (const float*)d_in[5];
    float* out = (float*)d_out;
    float* wsf = (float*)d_ws;
    int*   wsi = (int*)d_ws;

    k_stage1<<<S1BLOCKS, 256, 0, stream>>>(x, whole_w, rm_w, wsf, wsi, out);
    k_select<<<1, OUT_CH, 0, stream>>>(rm_q, wsf, wsi);
    k_conv<<<dim3(PT4, SPGRID, KSPLIT), 256, 0, stream>>>(whole_w, wsi, wsf);
    k_fin<<<SIZE_LIMIT, 256, 0, stream>>>(wsi, wsf, gamma, beta, out);
}